// Round 11
// baseline (2851.474 us; speedup 1.0000x reference)
//
#include <hip/hip_runtime.h>

#define BATCH 256
#define TT 512
#define CIN 512
#define UU 512
#define ZN 2048

typedef __attribute__((ext_vector_type(8))) short short8;
typedef __attribute__((ext_vector_type(4))) float f32x4;
typedef __attribute__((ext_vector_type(4))) unsigned u32x4;

__device__ __forceinline__ short f2bf(float f){
  unsigned u = __float_as_uint(f);
  u += 0x7fffu + ((u >> 16) & 1u);   // round-to-nearest-even
  return (short)(u >> 16);
}

// coherent (device-scope, MALL) 16B load with immediate offset
#define CLOAD(dst, p, OFFSTR) asm volatile( \
    "global_load_dwordx4 %0, %1, off offset:" OFFSTR " sc0 sc1" \
    : "=v"(dst) : "v"(p) : "memory")

__device__ __forceinline__ void st_coh_u32(void* p, unsigned v){
  asm volatile("global_store_dword %0, %1, off sc0 sc1" :: "v"(p), "v"(v) : "memory");
}

__device__ __forceinline__ float sigm(float x){ return 1.0f/(1.0f + __expf(-x)); }
__device__ __forceinline__ float tanh_fast(float x){ return 1.0f - 2.0f/(1.0f + __expf(2.0f*x)); }

// ---------------- transpose wx/wh: [512][2048] f32 -> [2048][512] bf16 ----------------
__global__ __launch_bounds__(256) void transpose_w_kernel(
    const float* __restrict__ wx, const float* __restrict__ wh,
    short* __restrict__ wxt, short* __restrict__ wht){
  const float* src = blockIdx.z ? wh : wx;
  short* dst = blockIdx.z ? wht : wxt;
  __shared__ float tile[32][33];
  const int nt = blockIdx.x << 5;
  const int kt = blockIdx.y << 5;
  const int tx = threadIdx.x & 31, ty = threadIdx.x >> 5;
  #pragma unroll
  for (int i = 0; i < 32; i += 8)
    tile[ty+i][tx] = src[(long)(kt+ty+i)*ZN + nt+tx];
  __syncthreads();
  #pragma unroll
  for (int i = 0; i < 32; i += 8)
    dst[(long)(nt+ty+i)*512 + kt+tx] = f2bf(tile[tx][ty+i]);
}

// ---------------- fully fused persistent LSTM ----------------
// 256 WGs x 512 thr (1/CU): bg = blockIdx&15 (16 rows), cg = blockIdx>>4
// (32 ucols). Wave wv's 16-col MFMA tile is GATE-INTERLEAVED: tile col cl ->
// z-col (cl&3)*512 + uc + wv*4 + (cl>>2), i.e. 4 ucols x 4 gates. wh AND wx
// register-resident (128 VGPR). Per step: stage x(t) (regs, prefetched) +
// poll/stage tagged h(t) into double-buffered LDS -> ONE syncthreads ->
// 32 MFMA (4 indep chains) -> z = zx + bias + keep*zh (uniform, exact mask)
// -> in-wave 4x4 transpose via LDS scratch (no barrier) -> 1 cell/thread
// epilogue -> tagged h store (the store IS the release; R10 protocol).
__global__ __launch_bounds__(512, 1) void lstm_fused_kernel(
    const float* __restrict__ x, const float* __restrict__ dones,
    const short* __restrict__ wht, const short* __restrict__ wxt,
    const float* __restrict__ bias, unsigned* __restrict__ ht0,
    unsigned* __restrict__ ht1, float* __restrict__ out){
  __shared__ short h_lds[2][8192];   // [k8=64][row=16][8]
  __shared__ short x_lds[2][8192];
  __shared__ float zw[2048];         // per-wave 256-word transpose scratch
  const int tid = threadIdx.x;
  const int l = tid & 63;
  const int wv = tid >> 6;           // 0..7
  const int bg = blockIdx.x & 15;
  const int cg = blockIdx.x >> 4;    // 0..15
  const int rb = bg << 4;
  const int uc = cg << 5;            // 32 ucols per WG
  const int hq = l >> 4;             // 0..3 (row-quad / k-seg)
  const int g_l = l & 3;             // gate of this lane's B-col
  const int u_l = (l >> 2) & 3;      // ucol-offset of this lane's B-col
  const int s_l = l & 3;             // cell row-in-quad (post-transpose)

  // ---- loop-invariant weights: z-col = g_l*512 + uc + wv*4 + u_l ----
  short8 bh[16], bx[16];
  const long zcol = (long)(g_l*512 + uc + wv*4 + u_l);
  {
    const short* whs = wht + zcol*512 + hq*8;
    const short* wxs = wxt + zcol*512 + hq*8;
    #pragma unroll
    for (int m = 0; m < 16; m++){
      bh[m] = *(const short8*)(whs + m*32);
      bx[m] = *(const short8*)(wxs + m*32);
    }
  }
  const float bias_l = bias[zcol];

  // ---- staging map: thread -> (row srow, 16 cols at skg*16) ----
  const int srow = tid & 15;
  const int skg  = tid >> 4;                        // 0..31
  const long hoff = (long)(rb + srow)*UU + skg*16;  // u32 index
  const int sdst = skg*256 + srow*8;                // u16 index
  const float* xsrc = x + ((long)(rb + srow)*TT)*CIN + skg*16;

  // ---- cell map (one per thread, post-transpose) ----
  const int crow = rb + hq*4 + s_l;
  const int cucol = uc + wv*4 + u_l;
  unsigned* const hst0 = ht0 + (long)crow*UU + cucol;
  unsigned* const hst1 = ht1 + (long)crow*UU + cucol;

  float c = 0.0f;
  float dn0, dn1, dn2, dn3, dn_c;
  {
    const long db = (long)(rb + hq*4)*TT;
    dn0 = dones[db];
    dn1 = dones[db + TT];
    dn2 = dones[db + 2*TT];
    dn3 = dones[db + 3*TT];
    dn_c = dones[(long)crow*TT];
  }
  float4 xr0 = *(const float4*)(xsrc);
  float4 xr1 = *(const float4*)(xsrc + 4);
  float4 xr2 = *(const float4*)(xsrc + 8);
  float4 xr3 = *(const float4*)(xsrc + 12);

  for (int t = 0; t < TT; t++){
    const int p = t & 1;
    // ---- stage x(t) from prefetched regs ----
    {
      short8 xv0, xv1;
      xv0[0]=f2bf(xr0.x); xv0[1]=f2bf(xr0.y); xv0[2]=f2bf(xr0.z); xv0[3]=f2bf(xr0.w);
      xv0[4]=f2bf(xr1.x); xv0[5]=f2bf(xr1.y); xv0[6]=f2bf(xr1.z); xv0[7]=f2bf(xr1.w);
      xv1[0]=f2bf(xr2.x); xv1[1]=f2bf(xr2.y); xv1[2]=f2bf(xr2.z); xv1[3]=f2bf(xr2.w);
      xv1[4]=f2bf(xr3.x); xv1[5]=f2bf(xr3.y); xv1[6]=f2bf(xr3.z); xv1[7]=f2bf(xr3.w);
      *(short8*)&x_lds[p][sdst      ] = xv0;
      *(short8*)&x_lds[p][sdst + 128] = xv1;
    }
    // ---- poll + stage tagged h(t) ----
    {
      const unsigned* hs = (p ? ht1 : ht0) + hoff;
      const unsigned tg = (unsigned)t;
      u32x4 w0, w1, w2, w3;
      for (;;){
        CLOAD(w0, hs, "0"); CLOAD(w1, hs, "16");
        CLOAD(w2, hs, "32"); CLOAD(w3, hs, "48");
        asm volatile("s_waitcnt vmcnt(0)" ::: "memory");
        const unsigned d = (w0[0]^tg)|(w0[1]^tg)|(w0[2]^tg)|(w0[3]^tg)
                         | (w1[0]^tg)|(w1[1]^tg)|(w1[2]^tg)|(w1[3]^tg)
                         | (w2[0]^tg)|(w2[1]^tg)|(w2[2]^tg)|(w2[3]^tg)
                         | (w3[0]^tg)|(w3[1]^tg)|(w3[2]^tg)|(w3[3]^tg);
        if (__all((int)((d & 0xffffu) == 0u))) break;
        __builtin_amdgcn_s_sleep(1);
      }
      u32x4 pa, pb;
      pa[0] = (w0[0]>>16) | (w0[1] & 0xffff0000u);
      pa[1] = (w0[2]>>16) | (w0[3] & 0xffff0000u);
      pa[2] = (w1[0]>>16) | (w1[1] & 0xffff0000u);
      pa[3] = (w1[2]>>16) | (w1[3] & 0xffff0000u);
      pb[0] = (w2[0]>>16) | (w2[1] & 0xffff0000u);
      pb[1] = (w2[2]>>16) | (w2[3] & 0xffff0000u);
      pb[2] = (w3[0]>>16) | (w3[1] & 0xffff0000u);
      pb[3] = (w3[2]>>16) | (w3[3] & 0xffff0000u);
      *(u32x4*)&h_lds[p][sdst      ] = pa;
      *(u32x4*)&h_lds[p][sdst + 128] = pb;
    }
    __syncthreads();
    // ---- 32 MFMA, 4 independent chains of 8 ----
    const short* ah = &h_lds[p][l*8];
    const short* ax = &x_lds[p][l*8];
    f32x4 h0 = {}, h1 = {}, x0 = {}, x1 = {};
    #pragma unroll
    for (int m = 0; m < 16; m += 2){
      h0 = __builtin_amdgcn_mfma_f32_16x16x32_bf16(*(const short8*)(ah + m*512),       bh[m],   h0, 0, 0, 0);
      x0 = __builtin_amdgcn_mfma_f32_16x16x32_bf16(*(const short8*)(ax + m*512),       bx[m],   x0, 0, 0, 0);
      h1 = __builtin_amdgcn_mfma_f32_16x16x32_bf16(*(const short8*)(ah + m*512 + 512), bh[m+1], h1, 0, 0, 0);
      x1 = __builtin_amdgcn_mfma_f32_16x16x32_bf16(*(const short8*)(ax + m*512 + 512), bx[m+1], x1, 0, 0, 0);
    }
    // ---- z = x-part + bias + keep*h-part (exact mask, uniform code) ----
    f32x4 zfull;
    zfull[0] = (x0[0] + x1[0] + bias_l) + (1.0f - dn0)*(h0[0] + h1[0]);
    zfull[1] = (x0[1] + x1[1] + bias_l) + (1.0f - dn1)*(h0[1] + h1[1]);
    zfull[2] = (x0[2] + x1[2] + bias_l) + (1.0f - dn2)*(h0[2] + h1[2]);
    zfull[3] = (x0[3] + x1[3] + bias_l) + (1.0f - dn3)*(h0[3] + h1[3]);
    // ---- in-wave 4x4 transpose (gates -> lane-local), no barrier ----
    *(f32x4*)&zw[wv*256 + l*4] = zfull;
    const int rbw = wv*256 + (hq*16 + u_l*4)*4 + s_l;
    const float z0 = zw[rbw];        // gate i
    const float z1 = zw[rbw + 4];    // gate f
    const float z2 = zw[rbw + 8];    // gate o
    const float z3 = zw[rbw + 12];   // gate u
    // ---- epilogue: one cell per thread ----
    const float keep = 1.0f - dn_c;
    const float gi = sigm(z0);
    const float gf = sigm(z1);
    const float go = sigm(z2);
    const float gu = tanh_fast(z3);
    const float cn = gf*(c*keep) + gi*gu;
    const float hn = go * tanh_fast(cn);
    c = cn;
    out[(long)crow*TT*UU + (long)t*UU + cucol] = hn;
    if (t == TT-1){
      float* s = out + (long)BATCH*TT*UU;
      s[(long)crow*2*UU + cucol] = cn;
      s[(long)crow*2*UU + UU + cucol] = hn;
    } else {
      // release = tagged store itself (device-coherent, fire-and-forget)
      const unsigned hv = ((unsigned)(unsigned short)f2bf(hn) << 16) | (unsigned)(t+1);
      st_coh_u32(p ? hst0 : hst1, hv);
      // prefetch next step (overlaps next poll's RTT)
      const float* xs = xsrc + (long)(t+1)*CIN;
      xr0 = *(const float4*)(xs);
      xr1 = *(const float4*)(xs + 4);
      xr2 = *(const float4*)(xs + 8);
      xr3 = *(const float4*)(xs + 12);
      const long db = (long)(rb + hq*4)*TT + (t+1);
      dn0 = dones[db];
      dn1 = dones[db + TT];
      dn2 = dones[db + 2*TT];
      dn3 = dones[db + 3*TT];
      dn_c = dones[(long)crow*TT + (t+1)];
    }
  }
}

extern "C" void kernel_launch(void* const* d_in, const int* in_sizes, int n_in,
                              void* d_out, int out_size, void* d_ws, size_t ws_size,
                              hipStream_t stream){
  const float* x     = (const float*)d_in[0];
  const float* dones = (const float*)d_in[1];
  const float* wx    = (const float*)d_in[2];
  const float* wh    = (const float*)d_in[3];
  const float* b     = (const float*)d_in[4];
  float* out = (float*)d_out;
  char* ws = (char*)d_ws;
  short* wx_t  = (short*)(ws);                    // 2,097,152 B
  short* wh_t  = (short*)(ws + 2097152L);         // 2,097,152 B
  unsigned* ht0 = (unsigned*)(ws + 4194304L);     //   524,288 B
  unsigned* ht1 = (unsigned*)(ws + 4718592L);     //   524,288 B

  hipMemsetAsync(ht0, 0, 524288, stream);
  hipMemsetAsync(ht1, 0, 524288, stream);
  transpose_w_kernel<<<dim3(64,16,2), 256, 0, stream>>>(wx, wh, wx_t, wh_t);
  lstm_fused_kernel<<<256, 512, 0, stream>>>(x, dones, wh_t, wx_t, b, ht0, ht1, out);
}